// Round 1
// baseline (768.210 us; speedup 1.0000x reference)
//
#include <hip/hip_runtime.h>

#define EPS 1e-5f
constexpr int BB = 8, NN = 4096;
constexpr float INV_CNT = 1.0f / (8.0f * 4096.0f);

// workspace layout (float offsets)
constexpr size_t OFF_H  = 0;              // 8*64*4096 = 2097152
constexpr size_t OFF_QP = 2097152;        // 8*16*4096 = 524288
constexpr size_t OFF_KP = 2621440;        // 524288
constexpr size_t OFF_VP = 3145728;        // 8*3*4096 = 98304
constexpr size_t OFF_ST = 3244032;        // 256 stats: [0]sum1 [64]ssq1 [128]sumq [144]ssqq [160]sumk [176]ssqk [192]sumv [195]ssqv
constexpr size_t OFF_PR = 3244288;        // 256 params: same layout but scale/shift

__device__ __forceinline__ void wave_red2(float& s, float& q) {
  #pragma unroll
  for (int off = 32; off; off >>= 1) { s += __shfl_xor(s, off); q += __shfl_xor(q, off); }
}

// ---- K1: h = w1 @ x, accumulate per-channel stats --------------------------
__global__ __launch_bounds__(256) void k1_mlp1(const float* __restrict__ x,
                                               const float* __restrict__ w1,
                                               float* __restrict__ h,
                                               float* __restrict__ stats) {
  __shared__ float w1s[192];
  int tx = threadIdx.x;
  if (tx < 192) w1s[tx] = w1[tx];
  __syncthreads();
  int b = blockIdx.x >> 4;
  int n = ((blockIdx.x & 15) << 8) + tx;
  float x0 = x[(size_t)(b*3+0)*NN + n];
  float x1 = x[(size_t)(b*3+1)*NN + n];
  float x2 = x[(size_t)(b*3+2)*NN + n];
  int lane = tx & 63;
  for (int c = 0; c < 64; ++c) {
    float v = fmaf(w1s[c*3], x0, fmaf(w1s[c*3+1], x1, w1s[c*3+2]*x2));
    h[((size_t)(b*64+c))*NN + n] = v;
    float s = v, q = v*v;
    wave_red2(s, q);
    if (lane == 0) { atomicAdd(&stats[c], s); atomicAdd(&stats[64+c], q); }
  }
}

// ---- F1: finalize BN1 ------------------------------------------------------
__global__ void f1_fin(const float* __restrict__ stats, const float* __restrict__ g1,
                       const float* __restrict__ b1, float* __restrict__ pr) {
  int c = threadIdx.x;  // 64
  float mean = stats[c] * INV_CNT;
  float var  = stats[64+c] * INV_CNT - mean*mean;
  float sc = g1[c] * rsqrtf(var + EPS);
  pr[c] = sc;
  pr[64+c] = fmaf(-mean, sc, b1[c]);
}

// ---- K3: BN1+LReLU -> feat (in regs) -> q/k/v pre + stats ------------------
__global__ __launch_bounds__(256) void k3_feat_qkv(
    const float* __restrict__ h, const float* __restrict__ w2,
    const float* __restrict__ wq, const float* __restrict__ wk,
    const float* __restrict__ wv, const float* __restrict__ pr,
    float* __restrict__ qp, float* __restrict__ kp, float* __restrict__ vp,
    float* __restrict__ stats) {
  __shared__ float w2s[8192];
  __shared__ float wqs[2048], wks[2048], wvs[384];
  __shared__ float s1s[64], h1s[64];
  int tx = threadIdx.x;
  for (int i = tx; i < 8192; i += 256) w2s[i] = w2[i];
  for (int i = tx; i < 2048; i += 256) { wqs[i] = wq[i]; wks[i] = wk[i]; }
  for (int i = tx; i < 384; i += 256) wvs[i] = wv[i];
  if (tx < 64) { s1s[tx] = pr[tx]; h1s[tx] = pr[64+tx]; }
  __syncthreads();
  int b = blockIdx.x >> 4;
  int n = ((blockIdx.x & 15) << 8) + tx;

  float hreg[64];
  #pragma unroll
  for (int c = 0; c < 64; ++c) {
    float v = fmaf(h[((size_t)(b*64+c))*NN + n], s1s[c], h1s[c]);
    hreg[c] = v > 0.f ? v : 0.2f*v;
  }
  float qa[16] = {}, ka[16] = {}, va[3] = {};
  for (int o = 0; o < 128; ++o) {
    float f0 = 0.f, f1 = 0.f, f2 = 0.f, f3 = 0.f;
    #pragma unroll
    for (int c = 0; c < 64; c += 4) {
      f0 = fmaf(w2s[o*64+c],   hreg[c],   f0);
      f1 = fmaf(w2s[o*64+c+1], hreg[c+1], f1);
      f2 = fmaf(w2s[o*64+c+2], hreg[c+2], f2);
      f3 = fmaf(w2s[o*64+c+3], hreg[c+3], f3);
    }
    float f = (f0+f1)+(f2+f3);
    #pragma unroll
    for (int d = 0; d < 16; ++d) {
      qa[d] = fmaf(wqs[d*128+o], f, qa[d]);
      ka[d] = fmaf(wks[d*128+o], f, ka[d]);
    }
    #pragma unroll
    for (int d = 0; d < 3; ++d) va[d] = fmaf(wvs[d*128+o], f, va[d]);
  }
  int lane = tx & 63;
  #pragma unroll
  for (int d = 0; d < 16; ++d) {
    qp[((size_t)(b*16+d))*NN + n] = qa[d];
    kp[((size_t)(b*16+d))*NN + n] = ka[d];
    float s = qa[d], q = qa[d]*qa[d];
    wave_red2(s, q);
    if (lane == 0) { atomicAdd(&stats[128+d], s); atomicAdd(&stats[144+d], q); }
    s = ka[d]; q = ka[d]*ka[d];
    wave_red2(s, q);
    if (lane == 0) { atomicAdd(&stats[160+d], s); atomicAdd(&stats[176+d], q); }
  }
  #pragma unroll
  for (int d = 0; d < 3; ++d) {
    vp[((size_t)(b*3+d))*NN + n] = va[d];
    float s = va[d], q = va[d]*va[d];
    wave_red2(s, q);
    if (lane == 0) { atomicAdd(&stats[192+d], s); atomicAdd(&stats[195+d], q); }
  }
}

// ---- F2: finalize BN2/3/4 --------------------------------------------------
__global__ void f2_fin(const float* __restrict__ stats,
                       const float* __restrict__ g2, const float* __restrict__ b2,
                       const float* __restrict__ g3, const float* __restrict__ b3,
                       const float* __restrict__ g4, const float* __restrict__ b4,
                       float* __restrict__ pr) {
  int i = threadIdx.x;
  if (i < 16) {
    float mean = stats[128+i] * INV_CNT;
    float var  = stats[144+i] * INV_CNT - mean*mean;
    float sc = g2[i] * rsqrtf(var + EPS);
    pr[128+i] = sc; pr[144+i] = fmaf(-mean, sc, b2[i]);
  } else if (i < 32) {
    int d = i - 16;
    float mean = stats[160+d] * INV_CNT;
    float var  = stats[176+d] * INV_CNT - mean*mean;
    float sc = g3[d] * rsqrtf(var + EPS);
    pr[160+d] = sc; pr[176+d] = fmaf(-mean, sc, b3[d]);
  } else if (i < 35) {
    int d = i - 32;
    float mean = stats[192+d] * INV_CNT;
    float var  = stats[195+d] * INV_CNT - mean*mean;
    float sc = g4[d] * rsqrtf(var + EPS);
    pr[192+d] = sc; pr[195+d] = fmaf(-mean, sc, b4[d]);
  }
}

// ---- K5: flash attention ---------------------------------------------------
// row n uses k[:,n] against columns q[:,m], values v[:,m]; softmax over m.
// 4 threads per row split m; shuffle-combine at the end.
__global__ __launch_bounds__(256) void k5_attn(
    const float* __restrict__ qp, const float* __restrict__ kp,
    const float* __restrict__ vp, const float* __restrict__ pr,
    const float* __restrict__ x, const float* __restrict__ alpha,
    float* __restrict__ out) {
  constexpr int CH = 128;
  __shared__ float qs[16*CH];
  __shared__ float vs[3*CH];
  int tx = threadIdx.x;
  int b = blockIdx.x >> 6;                      // 64 row-tiles per batch
  int n = ((blockIdx.x & 63) << 6) + (tx >> 2); // 64 rows per block
  int p = tx & 3;

  float kv[16];
  #pragma unroll
  for (int d = 0; d < 16; ++d) {
    float t = fmaf(kp[((size_t)(b*16+d))*NN + n], pr[160+d], pr[176+d]);
    kv[d] = t > 0.f ? t : 0.f;
  }

  float mcur = 0.f, l = 0.f, a0 = 0.f, a1 = 0.f, a2 = 0.f;  // scores >= 0
  for (int m0 = 0; m0 < NN; m0 += CH) {
    __syncthreads();
    for (int i = tx; i < 16*CH; i += 256) {
      int d = i >> 7, mm = i & (CH-1);
      float t = fmaf(qp[((size_t)(b*16+d))*NN + m0 + mm], pr[128+d], pr[144+d]);
      qs[i] = t > 0.f ? t : 0.f;
    }
    for (int i = tx; i < 3*CH; i += 256) {
      int d = i >> 7, mm = i & (CH-1);
      float t = fmaf(vp[((size_t)(b*3+d))*NN + m0 + mm], pr[192+d], pr[195+d]);
      vs[i] = t > 0.f ? t : 0.f;
    }
    __syncthreads();
    for (int mm = p; mm < CH; mm += 4) {
      float s0 = 0.f, s1 = 0.f, s2 = 0.f, s3 = 0.f;
      #pragma unroll
      for (int d = 0; d < 16; d += 4) {
        s0 = fmaf(kv[d],   qs[(d)*CH+mm],   s0);
        s1 = fmaf(kv[d+1], qs[(d+1)*CH+mm], s1);
        s2 = fmaf(kv[d+2], qs[(d+2)*CH+mm], s2);
        s3 = fmaf(kv[d+3], qs[(d+3)*CH+mm], s3);
      }
      float s = (s0+s1)+(s2+s3);
      float mn = fmaxf(mcur, s);
      float c  = __expf(mcur - mn);
      float pw = __expf(s - mn);
      l  = fmaf(l, c, pw);
      a0 = fmaf(a0, c, pw*vs[mm]);
      a1 = fmaf(a1, c, pw*vs[CH+mm]);
      a2 = fmaf(a2, c, pw*vs[2*CH+mm]);
      mcur = mn;
    }
  }
  // combine the 4 m-partials (adjacent lanes, xor 1 then 2)
  #pragma unroll
  for (int off = 1; off <= 2; off <<= 1) {
    float om = __shfl_xor(mcur, off);
    float ol = __shfl_xor(l, off);
    float o0 = __shfl_xor(a0, off);
    float o1 = __shfl_xor(a1, off);
    float o2 = __shfl_xor(a2, off);
    float mn = fmaxf(mcur, om);
    float c1 = __expf(mcur - mn), c2 = __expf(om - mn);
    l  = l*c1  + ol*c2;
    a0 = a0*c1 + o0*c2;
    a1 = a1*c1 + o1*c2;
    a2 = a2*c1 + o2*c2;
    mcur = mn;
  }
  if (p == 0) {
    float inv = 1.0f / l;
    float al = alpha[0];
    out[((size_t)(b*3+0))*NN + n] = fmaf(al, a0*inv, x[((size_t)(b*3+0))*NN + n]);
    out[((size_t)(b*3+1))*NN + n] = fmaf(al, a1*inv, x[((size_t)(b*3+1))*NN + n]);
    out[((size_t)(b*3+2))*NN + n] = fmaf(al, a2*inv, x[((size_t)(b*3+2))*NN + n]);
  }
}

extern "C" void kernel_launch(void* const* d_in, const int* in_sizes, int n_in,
                              void* d_out, int out_size, void* d_ws, size_t ws_size,
                              hipStream_t stream) {
  const float* x    = (const float*)d_in[0];
  const float* w1   = (const float*)d_in[1];
  const float* g1   = (const float*)d_in[2];
  const float* b1   = (const float*)d_in[3];
  const float* w2   = (const float*)d_in[4];
  const float* wq   = (const float*)d_in[5];
  const float* g2   = (const float*)d_in[6];
  const float* b2   = (const float*)d_in[7];
  const float* wk   = (const float*)d_in[8];
  const float* g3   = (const float*)d_in[9];
  const float* b3   = (const float*)d_in[10];
  const float* wv   = (const float*)d_in[11];
  const float* g4   = (const float*)d_in[12];
  const float* b4   = (const float*)d_in[13];
  const float* alpha= (const float*)d_in[14];
  float* out = (float*)d_out;
  float* ws  = (float*)d_ws;

  float* h    = ws + OFF_H;
  float* qpre = ws + OFF_QP;
  float* kpre = ws + OFF_KP;
  float* vpre = ws + OFF_VP;
  float* st   = ws + OFF_ST;
  float* pr   = ws + OFF_PR;

  hipMemsetAsync(st, 0, 256*sizeof(float), stream);
  k1_mlp1<<<128, 256, 0, stream>>>(x, w1, h, st);
  f1_fin<<<1, 64, 0, stream>>>(st, g1, b1, pr);
  k3_feat_qkv<<<128, 256, 0, stream>>>(h, w2, wq, wk, wv, pr, qpre, kpre, vpre, st);
  f2_fin<<<1, 64, 0, stream>>>(st, g2, b2, g3, b3, g4, b4, pr);
  k5_attn<<<512, 256, 0, stream>>>(qpre, kpre, vpre, pr, x, alpha, out);
}